// Round 12
// baseline (116.048 us; speedup 1.0000x reference)
//
#include <hip/hip_runtime.h>
#include <hip/hip_bf16.h>

#define N_ROWS 8192
#define H_DIM  1024
#define NUM_CLS 64
#define BM 128
#define BN 128
#define ROWB (H_DIM / 2)                 // 512 bytes per fp4 row
#define NBLK (N_ROWS / BM)               // 64 panels
#define SCALE_E8M0 0x79797979            // 121 -> 2^-6 per operand (x stored *64)
#define FIXSCALE 16777216.0              // 2^24 fixed-point for deterministic sum
#define GRID_K2 (8 * 264)                // 8 XCD slots x 264 (32 no-op blocks)

typedef float f32x4 __attribute__((ext_vector_type(4)));
typedef int   i32x4 __attribute__((ext_vector_type(4)));
typedef int   i32x8 __attribute__((ext_vector_type(8)));

__device__ __forceinline__ float fast_exp2(float x) {
    float r;
    asm("v_exp_f32 %0, %1" : "=v"(r) : "v"(x));
    return r;
}

__device__ __forceinline__ void async_copy16(void* lds, const void* g) {
    __builtin_amdgcn_global_load_lds(
        (const __attribute__((address_space(1))) void*)g,
        (__attribute__((address_space(3))) void*)lds, 16, 0, 0);
}

// e2m1 encode of f (pre-scaled): codes 0..7 = {0,.5,1,1.5,2,3,4,6}, bit3 = sign
__device__ __forceinline__ unsigned enc_fp4(float f) {
    const float a = fabsf(f);
    unsigned c = (unsigned)(a > 0.25f) + (unsigned)(a > 0.75f) +
                 (unsigned)(a > 1.25f) + (unsigned)(a > 1.75f) +
                 (unsigned)(a > 2.5f)  + (unsigned)(a > 3.5f) +
                 (unsigned)(a > 5.0f);
    return c | ((__float_as_uint(f) >> 31) << 3);
}

// --- Kernel 1: row-normalize fp32 -> fp4 e2m1 (x*64); 4 rows/block ---
// Also builds the global label histogram (int atomics = deterministic).
__global__ __launch_bounds__(256) void norm_kernel(const float* __restrict__ in,
                                                   ushort* __restrict__ out,
                                                   const int* __restrict__ labels,
                                                   int* __restrict__ ghist) {
    if (threadIdx.x < 4)
        atomicAdd(&ghist[labels[blockIdx.x * 4 + threadIdx.x]], 1);
    const int row  = blockIdx.x * 4 + (threadIdx.x >> 6);
    const int lane = threadIdx.x & 63;
    const float4* src = reinterpret_cast<const float4*>(in + (size_t)row * H_DIM);
    float4 v[4];
    float ss = 0.f;
#pragma unroll
    for (int i = 0; i < 4; ++i) {
        v[i] = src[i * 64 + lane];                    // coalesced 16B/lane
        ss += v[i].x * v[i].x + v[i].y * v[i].y + v[i].z * v[i].z + v[i].w * v[i].w;
    }
#pragma unroll
    for (int d = 1; d < 64; d <<= 1) ss += __shfl_xor(ss, d, 64);
    const float inv = 64.0f / fmaxf(sqrtf(ss), 1e-12f);   // *64: fp4 resolution band
    ushort* op = out + (size_t)row * (ROWB / 2);          // 256 ushorts per row
#pragma unroll
    for (int i = 0; i < 4; ++i) {
        const unsigned b0 = enc_fp4(v[i].x * inv) | (enc_fp4(v[i].y * inv) << 4);
        const unsigned b1 = enc_fp4(v[i].z * inv) | (enc_fp4(v[i].w * inv) << 4);
        op[i * 64 + lane] = (ushort)(b0 | (b1 << 8));
    }
}

// 28 off-diagonal 8x8-panel super-tiles (a<b), packed a<<3|b, row-major
__device__ __constant__ unsigned char OFF_TBL[28] = {
    1, 2, 3, 4, 5, 6, 7,
    10, 11, 12, 13, 14, 15,
    19, 20, 21, 22, 23,
    28, 29, 30, 31,
    37, 38, 39,
    46, 47,
    55
};

// ---- Kernel 2: symmetric fused Gram + exp + masked row/col partials ----
// MX-fp4, 2-buffer dbuf, COUNTED vmcnt(4): prefetch(s+1) stays in flight
// across the whole compute phase; drain-to-0 only at the last step (T3/T4).
__global__ __launch_bounds__(256, 4)
void simloss_kernel(const unsigned char* __restrict__ xq, const int* __restrict__ labels,
                    float* __restrict__ ppos, float* __restrict__ pall) {
    __shared__ __align__(16) unsigned char As[2][BM * 64];   // 2 x 8 KB
    __shared__ __align__(16) unsigned char Bs[2][BN * 64];   // 2 x 8 KB

    // ---- super-tile decode: xcd = blockIdx%8 owns a fixed tile list ----
    const int xcd = blockIdx.x & 7;
    const int n   = blockIdx.x >> 3;     // 0..263 within this XCD
    int I, J;
    if (xcd < 4) {                        // 4 off-diag tiles (256 blocks)
        if (n >= 256) return;
        const int t = OFF_TBL[xcd * 4 + (n >> 6)];
        I = (t >> 3) * 8 + ((n >> 3) & 7);
        J = (t & 7) * 8 + (n & 7);
    } else if (n < 192) {                 // 3 off-diag tiles
        const int t = OFF_TBL[16 + (xcd - 4) * 3 + (n >> 6)];
        I = (t >> 3) * 8 + ((n >> 3) & 7);
        J = (t & 7) * 8 + (n & 7);
    } else {                              // 2 diag tiles (36 blocks each)
        int n2 = n - 192;                 // 0..71
        const int D = (xcd - 4) * 2 + (n2 >= 36 ? 1 : 0);
        int t2 = (n2 >= 36) ? n2 - 36 : n2;
        int i = 0;
        while (t2 >= 8 - i) { t2 -= 8 - i; ++i; }
        I = D * 8 + i;
        J = D * 8 + i + t2;
    }
    const bool diag = (I == J);
    const int row0 = I * BM, col0 = J * BN;

    const int tid  = threadIdx.x;
    const int lane = tid & 63;
    const int wid  = tid >> 6;
    const int wr = wid >> 1, wc = wid & 1;
    const int l15 = lane & 15, lq = lane >> 4;

    f32x4 acc[4][4];
#pragma unroll
    for (int m = 0; m < 4; ++m)
#pragma unroll
        for (int n2 = 0; n2 < 4; ++n2) acc[m][n2] = (f32x4){0.f, 0.f, 0.f, 0.f};

    // read slot: logical chunk lq at phys slot lq ^ ((row>>1)&3) -> 2-way free
    const int rslot = (lq ^ ((l15 >> 1) & 3)) * 16;
    const i32x4 z4 = {0, 0, 0, 0};

    // STAGE one K-step (64 B of K) into buffer b: 4 issues/thread, linear LDS
    // dest (wave-uniform base + lane*16); source chunk pre-swizzled (rule #21)
#define STAGE(b, k0b)                                                          \
    do {                                                                       \
        _Pragma("unroll")                                                      \
        for (int q = 0; q < 2; ++q) {                                          \
            const int seg = wid * 2 + q;                                       \
            const int row = seg * 16 + (lane >> 2);                            \
            const int ls  = (lane & 3) ^ ((row >> 1) & 3);                     \
            async_copy16(&As[b][seg * 1024],                                   \
                         &xq[(size_t)(row0 + row) * ROWB + (k0b) + ls * 16]);  \
            async_copy16(&Bs[b][seg * 1024],                                   \
                         &xq[(size_t)(col0 + row) * ROWB + (k0b) + ls * 16]);  \
        }                                                                      \
    } while (0)

    // prologue: stage step 0 into buf 0 (no drain -- the loop's counted
    // vmcnt(4) at s=0 waits exactly these 4 issues)
    STAGE(0, 0);

#pragma unroll
    for (int s = 0; s < 8; ++s) {         // 8 K-steps x 128 elems
        const int buf = s & 1;
        if (s + 1 < 8) {
            STAGE(buf ^ 1, (s + 1) * 64); // prefetch -> other buffer (4 issues)
            // wait until only the 4 newest (prefetch) remain: tile-s landed,
            // tile-(s+1) stays in flight under the whole compute phase (T4)
            asm volatile("s_waitcnt vmcnt(4)" ::: "memory");
        } else {
            asm volatile("s_waitcnt vmcnt(0)" ::: "memory");
        }
        __builtin_amdgcn_s_barrier();     // all waves' tile-s data in LDS
        asm volatile("" ::: "memory");    // no LDS-read hoist above barrier

        i32x8 av[4], bv[4];
#pragma unroll
        for (int m = 0; m < 4; ++m) {
            const i32x4 lo = *reinterpret_cast<const i32x4*>(
                &As[buf][(wr * 64 + m * 16 + l15) * 64 + rslot]);
            av[m] = __builtin_shufflevector(lo, z4, 0, 1, 2, 3, 4, 5, 6, 7);
        }
#pragma unroll
        for (int n2 = 0; n2 < 4; ++n2) {
            const i32x4 lo = *reinterpret_cast<const i32x4*>(
                &Bs[buf][(wc * 64 + n2 * 16 + l15) * 64 + rslot]);
            bv[n2] = __builtin_shufflevector(lo, z4, 0, 1, 2, 3, 4, 5, 6, 7);
        }
#pragma unroll
        for (int m = 0; m < 4; ++m)
#pragma unroll
            for (int n2 = 0; n2 < 4; ++n2)
                acc[m][n2] = __builtin_amdgcn_mfma_scale_f32_16x16x128_f8f6f4(
                    av[m], bv[n2], acc[m][n2],
                    4 /*cbsz: fp4 e2m1*/, 4 /*blgp: fp4 e2m1*/,
                    0, SCALE_E8M0, 0, SCALE_E8M0);

        asm volatile("" ::: "memory");    // no LDS-read sink below barrier
        __builtin_amdgcn_s_barrier();     // reads of buf done before next STAGE
    }
#undef STAGE

    // ---- epilogue: exp + masked row sums AND column sums ----
    int lab_r[16];
#pragma unroll
    for (int m = 0; m < 4; ++m)
#pragma unroll
        for (int r = 0; r < 4; ++r)
            lab_r[m * 4 + r] = labels[row0 + wr * 64 + m * 16 + lq * 4 + r];

    float rs_pos[16], rs_all[16];
#pragma unroll
    for (int i = 0; i < 16; ++i) { rs_pos[i] = 0.f; rs_all[i] = 0.f; }
    float cs_pos[4], cs_all[4];
#pragma unroll
    for (int n2 = 0; n2 < 4; ++n2) { cs_pos[n2] = 0.f; cs_all[n2] = 0.f; }

#pragma unroll
    for (int n2 = 0; n2 < 4; ++n2) {
        const int colg = col0 + wc * 64 + n2 * 16 + l15;
        const int lab_c = labels[colg];
#pragma unroll
        for (int m = 0; m < 4; ++m) {
#pragma unroll
            for (int r = 0; r < 4; ++r) {
                const int rowg = row0 + wr * 64 + m * 16 + lq * 4 + r;
                const float e = fast_exp2(acc[m][n2][r] * 14.4269504088896340736f);
                const bool self = (rowg == colg);       // only possible when diag
                const bool pos  = (lab_c == lab_r[m * 4 + r]) && !self;
                const float ea = self ? 0.f : e;
                const float ep = pos ? e : 0.f;
                rs_all[m * 4 + r] += ea;
                rs_pos[m * 4 + r] += ep;
                cs_all[n2] += ea;
                cs_pos[n2] += ep;
            }
        }
    }

#pragma unroll
    for (int i = 0; i < 16; ++i) {
#pragma unroll
        for (int d = 1; d < 16; d <<= 1) {
            rs_pos[i] += __shfl_xor(rs_pos[i], d, 64);
            rs_all[i] += __shfl_xor(rs_all[i], d, 64);
        }
    }
#pragma unroll
    for (int n2 = 0; n2 < 4; ++n2) {
#pragma unroll
        for (int d = 16; d < 64; d <<= 1) {
            cs_pos[n2] += __shfl_xor(cs_pos[n2], d, 64);
            cs_all[n2] += __shfl_xor(cs_all[n2], d, 64);
        }
    }

    __syncthreads();                       // all LDS fragment reads done
    float* sc = (float*)&As[0][0];
    float* rowpos = sc;                    // [2][128] indexed [wc][localrow]
    float* rowall = sc + 256;
    float* colpos = sc + 512;              // [2][128] indexed [wr][localcol]
    float* colall = sc + 768;              // 4 KB total
    if (l15 == 0) {
#pragma unroll
        for (int i = 0; i < 16; ++i) {
            const int m = i >> 2, r = i & 3;
            const int lr = wr * 64 + m * 16 + lq * 4 + r;
            rowpos[wc * 128 + lr] = rs_pos[i];
            rowall[wc * 128 + lr] = rs_all[i];
        }
    }
    if (lq == 0 && !diag) {
#pragma unroll
        for (int n2 = 0; n2 < 4; ++n2) {
            const int lc = wc * 64 + n2 * 16 + l15;
            colpos[wr * 128 + lc] = cs_pos[n2];
            colall[wr * 128 + lc] = cs_all[n2];
        }
    }
    __syncthreads();

    // partial-slot scheme: row-side -> slot J, col-side -> slot I (exactly once)
    if (tid < 128) {
        const float rp = rowpos[tid] + rowpos[128 + tid];
        const float ra = rowall[tid] + rowall[128 + tid];
        ppos[(size_t)J * N_ROWS + row0 + tid] = rp;
        pall[(size_t)J * N_ROWS + row0 + tid] = ra;
    } else if (!diag) {
        const int t2 = tid - 128;
        const float cp = colpos[t2] + colpos[128 + t2];
        const float ca = colall[t2] + colall[128 + t2];
        ppos[(size_t)I * N_ROWS + col0 + t2] = cp;
        pall[(size_t)I * N_ROWS + col0 + t2] = ca;
    }
}

// ---- Kernel 3: fused finalize (deterministic int64 fixed-point + ticket) ----
__global__ __launch_bounds__(256)
void finalize_kernel(const int* __restrict__ labels, const float* __restrict__ ppos,
                     const float* __restrict__ pall, const int* __restrict__ ghist,
                     unsigned long long* __restrict__ acc, float* __restrict__ out) {
    __shared__ float sred[4];
    __shared__ int scnt[4];
    const int tid = threadIdx.x;

    float lsum = 0.f;
    int vcnt = 0;
    if (tid < 128) {
        const int i = blockIdx.x * 128 + tid;
        float p = 0.f, a = 0.f;
#pragma unroll
        for (int s = 0; s < NBLK; ++s) {
            p += ppos[(size_t)s * N_ROWS + i];
            a += pall[(size_t)s * N_ROWS + i];
        }
        const int cnt = ghist[labels[i]] - 1;
        if (cnt > 0) {
            lsum = logf(a) - logf(p) + logf((float)cnt);   // >= 0 structurally
            vcnt = 1;
        }
    }
    const int lane = tid & 63, wid = tid >> 6;
#pragma unroll
    for (int d = 1; d < 64; d <<= 1) {
        lsum += __shfl_xor(lsum, d, 64);
        vcnt += __shfl_xor(vcnt, d, 64);
    }
    if (lane == 0) { sred[wid] = lsum; scnt[wid] = vcnt; }
    __syncthreads();
    if (tid == 0) {
        const double bs = (double)(sred[0] + sred[1] + sred[2] + sred[3]);
        const unsigned long long S = (unsigned long long)(bs * FIXSCALE + 0.5);
        const unsigned long long C = (unsigned long long)(scnt[0] + scnt[1] + scnt[2] + scnt[3]);
        atomicAdd(&acc[1], S);
        atomicAdd(&acc[2], C);
        __threadfence();
        const unsigned long long tk = atomicAdd(&acc[0], 1ULL);
        if (tk == (unsigned long long)(NBLK - 1)) {
            volatile unsigned long long* va = acc;
            const double St = (double)va[1];
            const double Ct = (double)va[2];
            out[0] = (float)(St / FIXSCALE / Ct);
        }
    }
}

extern "C" void kernel_launch(void* const* d_in, const int* in_sizes, int n_in,
                              void* d_out, int out_size, void* d_ws, size_t ws_size,
                              hipStream_t stream) {
    const float* emb   = (const float*)d_in[0];
    const int* labels  = (const int*)d_in[1];
    float* out         = (float*)d_out;
    char* ws           = (char*)d_ws;

    unsigned char* xq = (unsigned char*)ws;                      // 4 MB fp4 (x*64)
    float* ppos = (float*)(ws + (size_t)N_ROWS * ROWB);          // NBLK*N floats (2 MB)
    float* pall = ppos + (size_t)NBLK * N_ROWS;                  // NBLK*N floats (2 MB)
    unsigned long long* acc = (unsigned long long*)(pall + (size_t)NBLK * N_ROWS);
    int* ghist = (int*)(acc + 4);                                // 64 ints

    // zero ticket/sum/cnt + histogram (graph-capture-safe async memset)
    hipMemsetAsync(acc, 0, 4 * sizeof(unsigned long long) + NUM_CLS * sizeof(int),
                   stream);
    norm_kernel<<<N_ROWS / 4, 256, 0, stream>>>(emb, (ushort*)xq, labels, ghist);
    simloss_kernel<<<GRID_K2, 256, 0, stream>>>(xq, labels, ppos, pall);
    finalize_kernel<<<NBLK, 256, 0, stream>>>(labels, ppos, pall, ghist, acc, out);
}

// Round 13
// 101.802 us; speedup vs baseline: 1.1399x; 1.1399x over previous
//
#include <hip/hip_runtime.h>
#include <hip/hip_bf16.h>

#define N_ROWS 8192
#define H_DIM  1024
#define NUM_CLS 64
#define BM 128
#define BN 128
#define NBLK (N_ROWS / BM)               // 64 panels
#define KSTRIDE ((size_t)N_ROWS * 16)    // bytes per kchunk plane (131072)
#define SCALE_E8M0 0x79797979            // 121 -> 2^-6 per operand (x stored *64)
#define FIXSCALE 16777216.0              // 2^24 fixed-point for deterministic sum
#define GRID_K2 (8 * 264)                // 8 XCD slots x 264 (32 no-op blocks)

typedef float f32x4 __attribute__((ext_vector_type(4)));
typedef int   i32x4 __attribute__((ext_vector_type(4)));
typedef int   i32x8 __attribute__((ext_vector_type(8)));

__device__ __forceinline__ float fast_exp2(float x) {
    float r;
    asm("v_exp_f32 %0, %1" : "=v"(r) : "v"(x));
    return r;
}

// e2m1 encode of f (pre-scaled): codes 0..7 = {0,.5,1,1.5,2,3,4,6}, bit3 = sign
__device__ __forceinline__ unsigned enc_fp4(float f) {
    const float a = fabsf(f);
    unsigned c = (unsigned)(a > 0.25f) + (unsigned)(a > 0.75f) +
                 (unsigned)(a > 1.25f) + (unsigned)(a > 1.75f) +
                 (unsigned)(a > 2.5f)  + (unsigned)(a > 3.5f) +
                 (unsigned)(a > 5.0f);
    return c | ((__float_as_uint(f) >> 31) << 3);
}

// --- Kernel 1: row-normalize fp32 -> fp4 e2m1 (x*64), K-MAJOR layout ---
// xqT[kchunk][row] : 16 B per (row, kchunk of 32 elems). 8 rows/block.
// Also builds the global label histogram (int atomics = deterministic).
__global__ __launch_bounds__(256) void norm_kernel(const float* __restrict__ in,
                                                   unsigned char* __restrict__ xqT,
                                                   const int* __restrict__ labels,
                                                   int* __restrict__ ghist) {
    if (threadIdx.x < 8)
        atomicAdd(&ghist[labels[blockIdx.x * 8 + threadIdx.x]], 1);
    const int wid  = threadIdx.x >> 6, lane = threadIdx.x & 63;
    const int l32  = lane & 31;                       // this lane's kchunk
    const int row  = blockIdx.x * 8 + wid * 2 + (lane >> 5);
    const float4* src = reinterpret_cast<const float4*>(in + (size_t)row * H_DIM)
                        + l32 * 8;                    // 32 contiguous elems/lane
    float4 v[8];
    float ss = 0.f;
#pragma unroll
    for (int i = 0; i < 8; ++i) {
        v[i] = src[i];
        ss += v[i].x * v[i].x + v[i].y * v[i].y + v[i].z * v[i].z + v[i].w * v[i].w;
    }
#pragma unroll
    for (int d = 1; d < 32; d <<= 1) ss += __shfl_xor(ss, d, 64);  // 32-lane row sum
    const float inv = 64.0f / fmaxf(sqrtf(ss), 1e-12f);
    i32x4 dw;
#pragma unroll
    for (int j = 0; j < 4; ++j) {
        unsigned d = 0;
#pragma unroll
        for (int k = 0; k < 8; ++k) {
            const int e = j * 8 + k;
            const float f = ((const float*)&v[e >> 2])[e & 3] * inv;
            d |= enc_fp4(f) << (4 * k);
        }
        dw[j] = (int)d;
    }
    *reinterpret_cast<i32x4*>(xqT + (size_t)l32 * KSTRIDE + (size_t)row * 16) = dw;
}

// 28 off-diagonal 8x8-panel super-tiles (a<b), packed a<<3|b, row-major
__device__ __constant__ unsigned char OFF_TBL[28] = {
    1, 2, 3, 4, 5, 6, 7,
    10, 11, 12, 13, 14, 15,
    19, 20, 21, 22, 23,
    28, 29, 30, 31,
    37, 38, 39,
    46, 47,
    55
};

// ---- Kernel 2: symmetric fused Gram + exp + masked row/col partials ----
// WAVE-AUTONOMOUS: no barriers, no staging LDS. Fragments load direct
// global->VGPR (coalesced via K-major layout, L2-hot via super-tile XCD
// co-schedule), register double-buffer, compiler-counted vmcnt prefetch.
__global__ __launch_bounds__(256)
void simloss_kernel(const unsigned char* __restrict__ xqT, const int* __restrict__ labels,
                    float* __restrict__ ppos, float* __restrict__ pall) {
    __shared__ float sc[1024];            // 4 KB epilogue scratch only

    // ---- super-tile decode: xcd = blockIdx%8 owns a fixed tile list ----
    const int xcd = blockIdx.x & 7;
    const int n   = blockIdx.x >> 3;     // 0..263 within this XCD
    int I, J;
    if (xcd < 4) {                        // 4 off-diag tiles (256 blocks)
        if (n >= 256) return;
        const int t = OFF_TBL[xcd * 4 + (n >> 6)];
        I = (t >> 3) * 8 + ((n >> 3) & 7);
        J = (t & 7) * 8 + (n & 7);
    } else if (n < 192) {                 // 3 off-diag tiles
        const int t = OFF_TBL[16 + (xcd - 4) * 3 + (n >> 6)];
        I = (t >> 3) * 8 + ((n >> 3) & 7);
        J = (t & 7) * 8 + (n & 7);
    } else {                              // 2 diag tiles (36 blocks each)
        int n2 = n - 192;                 // 0..71
        const int D = (xcd - 4) * 2 + (n2 >= 36 ? 1 : 0);
        int t2 = (n2 >= 36) ? n2 - 36 : n2;
        int i = 0;
        while (t2 >= 8 - i) { t2 -= 8 - i; ++i; }
        I = D * 8 + i;
        J = D * 8 + i + t2;
    }
    const bool diag = (I == J);
    const int row0 = I * BM, col0 = J * BN;

    const int tid  = threadIdx.x;
    const int lane = tid & 63;
    const int wid  = tid >> 6;
    const int wr = wid >> 1, wc = wid & 1;
    const int l15 = lane & 15, lq = lane >> 4;

    f32x4 acc[4][4];
#pragma unroll
    for (int m = 0; m < 4; ++m)
#pragma unroll
        for (int n2 = 0; n2 < 4; ++n2) acc[m][n2] = (f32x4){0.f, 0.f, 0.f, 0.f};

    // fragment bases: lane (l15,lq) reads 16 B at (row, kc = s*4+lq):
    // addr = kc*KSTRIDE + row*16 -> lanes l15 consecutive rows = 256 B
    // contiguous per lq group (coalesced); kc planes 128 KB apart.
    const unsigned char* Ap = xqT + (size_t)lq * KSTRIDE + (size_t)(row0 + wr * 64 + l15) * 16;
    const unsigned char* Bp = xqT + (size_t)lq * KSTRIDE + (size_t)(col0 + wc * 64 + l15) * 16;
    const i32x4 z4 = {0, 0, 0, 0};

#define LOADS(DA, DB, S)                                                       \
    do {                                                                       \
        _Pragma("unroll")                                                      \
        for (int m = 0; m < 4; ++m)                                            \
            DA[m] = *reinterpret_cast<const i32x4*>(                           \
                Ap + (size_t)(S) * 4 * KSTRIDE + m * 256);                     \
        _Pragma("unroll")                                                      \
        for (int n2 = 0; n2 < 4; ++n2)                                         \
            DB[n2] = *reinterpret_cast<const i32x4*>(                          \
                Bp + (size_t)(S) * 4 * KSTRIDE + n2 * 256);                    \
    } while (0)

#define MFMA_STEP(AA, BB)                                                      \
    do {                                                                       \
        __builtin_amdgcn_s_setprio(1);                                         \
        _Pragma("unroll")                                                      \
        for (int m = 0; m < 4; ++m) {                                          \
            const i32x8 a8 = __builtin_shufflevector(AA[m], z4,                \
                                                     0, 1, 2, 3, 4, 5, 6, 7);  \
            _Pragma("unroll")                                                  \
            for (int n2 = 0; n2 < 4; ++n2) {                                   \
                const i32x8 b8 = __builtin_shufflevector(BB[n2], z4,           \
                                                         0, 1, 2, 3, 4, 5, 6, 7); \
                acc[m][n2] = __builtin_amdgcn_mfma_scale_f32_16x16x128_f8f6f4( \
                    a8, b8, acc[m][n2], 4, 4, 0, SCALE_E8M0, 0, SCALE_E8M0);   \
            }                                                                  \
        }                                                                      \
        __builtin_amdgcn_s_setprio(0);                                         \
    } while (0)

    // register double-buffer, static indices (rule #20), no barriers:
    // compiler's per-use vmcnt keeps the next step's 8 loads in flight
    // under the current step's 16 MFMAs.
    i32x4 a0[4], b0[4], a1[4], b1[4];
    LOADS(a0, b0, 0);
#pragma unroll
    for (int it = 0; it < 4; ++it) {      // 8 K-steps of 128 elems
        LOADS(a1, b1, 2 * it + 1);
        MFMA_STEP(a0, b0);
        if (it < 3) LOADS(a0, b0, 2 * it + 2);
        MFMA_STEP(a1, b1);
    }
#undef LOADS
#undef MFMA_STEP

    // ---- epilogue: exp + masked row sums AND column sums ----
    int lab_r[16];
#pragma unroll
    for (int m = 0; m < 4; ++m)
#pragma unroll
        for (int r = 0; r < 4; ++r)
            lab_r[m * 4 + r] = labels[row0 + wr * 64 + m * 16 + lq * 4 + r];

    float rs_pos[16], rs_all[16];
#pragma unroll
    for (int i = 0; i < 16; ++i) { rs_pos[i] = 0.f; rs_all[i] = 0.f; }
    float cs_pos[4], cs_all[4];
#pragma unroll
    for (int n2 = 0; n2 < 4; ++n2) { cs_pos[n2] = 0.f; cs_all[n2] = 0.f; }

#pragma unroll
    for (int n2 = 0; n2 < 4; ++n2) {
        const int colg = col0 + wc * 64 + n2 * 16 + l15;
        const int lab_c = labels[colg];
#pragma unroll
        for (int m = 0; m < 4; ++m) {
#pragma unroll
            for (int r = 0; r < 4; ++r) {
                const int rowg = row0 + wr * 64 + m * 16 + lq * 4 + r;
                const float e = fast_exp2(acc[m][n2][r] * 14.4269504088896340736f);
                const bool self = (rowg == colg);       // only possible when diag
                const bool pos  = (lab_c == lab_r[m * 4 + r]) && !self;
                const float ea = self ? 0.f : e;
                const float ep = pos ? e : 0.f;
                rs_all[m * 4 + r] += ea;
                rs_pos[m * 4 + r] += ep;
                cs_all[n2] += ea;
                cs_pos[n2] += ep;
            }
        }
    }

#pragma unroll
    for (int i = 0; i < 16; ++i) {
#pragma unroll
        for (int d = 1; d < 16; d <<= 1) {
            rs_pos[i] += __shfl_xor(rs_pos[i], d, 64);
            rs_all[i] += __shfl_xor(rs_all[i], d, 64);
        }
    }
#pragma unroll
    for (int n2 = 0; n2 < 4; ++n2) {
#pragma unroll
        for (int d = 16; d < 64; d <<= 1) {
            cs_pos[n2] += __shfl_xor(cs_pos[n2], d, 64);
            cs_all[n2] += __shfl_xor(cs_all[n2], d, 64);
        }
    }

    float* rowpos = sc;                    // [2][128] indexed [wc][localrow]
    float* rowall = sc + 256;
    float* colpos = sc + 512;              // [2][128] indexed [wr][localcol]
    float* colall = sc + 768;
    if (l15 == 0) {
#pragma unroll
        for (int i = 0; i < 16; ++i) {
            const int m = i >> 2, r = i & 3;
            const int lr = wr * 64 + m * 16 + lq * 4 + r;
            rowpos[wc * 128 + lr] = rs_pos[i];
            rowall[wc * 128 + lr] = rs_all[i];
        }
    }
    if (lq == 0 && !diag) {
#pragma unroll
        for (int n2 = 0; n2 < 4; ++n2) {
            const int lc = wc * 64 + n2 * 16 + l15;
            colpos[wr * 128 + lc] = cs_pos[n2];
            colall[wr * 128 + lc] = cs_all[n2];
        }
    }
    __syncthreads();

    // partial-slot scheme: row-side -> slot J, col-side -> slot I (exactly once)
    if (tid < 128) {
        const float rp = rowpos[tid] + rowpos[128 + tid];
        const float ra = rowall[tid] + rowall[128 + tid];
        ppos[(size_t)J * N_ROWS + row0 + tid] = rp;
        pall[(size_t)J * N_ROWS + row0 + tid] = ra;
    } else if (!diag) {
        const int t2 = tid - 128;
        const float cp = colpos[t2] + colpos[128 + t2];
        const float ca = colall[t2] + colall[128 + t2];
        ppos[(size_t)I * N_ROWS + col0 + t2] = cp;
        pall[(size_t)I * N_ROWS + col0 + t2] = ca;
    }
}

// ---- Kernel 3: fused finalize (deterministic int64 fixed-point + ticket) ----
__global__ __launch_bounds__(256)
void finalize_kernel(const int* __restrict__ labels, const float* __restrict__ ppos,
                     const float* __restrict__ pall, const int* __restrict__ ghist,
                     unsigned long long* __restrict__ acc, float* __restrict__ out) {
    __shared__ float sred[4];
    __shared__ int scnt[4];
    const int tid = threadIdx.x;

    float lsum = 0.f;
    int vcnt = 0;
    if (tid < 128) {
        const int i = blockIdx.x * 128 + tid;
        float p = 0.f, a = 0.f;
#pragma unroll
        for (int s = 0; s < NBLK; ++s) {
            p += ppos[(size_t)s * N_ROWS + i];
            a += pall[(size_t)s * N_ROWS + i];
        }
        const int cnt = ghist[labels[i]] - 1;
        if (cnt > 0) {
            lsum = logf(a) - logf(p) + logf((float)cnt);   // >= 0 structurally
            vcnt = 1;
        }
    }
    const int lane = tid & 63, wid = tid >> 6;
#pragma unroll
    for (int d = 1; d < 64; d <<= 1) {
        lsum += __shfl_xor(lsum, d, 64);
        vcnt += __shfl_xor(vcnt, d, 64);
    }
    if (lane == 0) { sred[wid] = lsum; scnt[wid] = vcnt; }
    __syncthreads();
    if (tid == 0) {
        const double bs = (double)(sred[0] + sred[1] + sred[2] + sred[3]);
        const unsigned long long S = (unsigned long long)(bs * FIXSCALE + 0.5);
        const unsigned long long C = (unsigned long long)(scnt[0] + scnt[1] + scnt[2] + scnt[3]);
        atomicAdd(&acc[1], S);
        atomicAdd(&acc[2], C);
        __threadfence();
        const unsigned long long tk = atomicAdd(&acc[0], 1ULL);
        if (tk == (unsigned long long)(NBLK - 1)) {
            volatile unsigned long long* va = acc;
            const double St = (double)va[1];
            const double Ct = (double)va[2];
            out[0] = (float)(St / FIXSCALE / Ct);
        }
    }
}

extern "C" void kernel_launch(void* const* d_in, const int* in_sizes, int n_in,
                              void* d_out, int out_size, void* d_ws, size_t ws_size,
                              hipStream_t stream) {
    const float* emb   = (const float*)d_in[0];
    const int* labels  = (const int*)d_in[1];
    float* out         = (float*)d_out;
    char* ws           = (char*)d_ws;

    unsigned char* xqT = (unsigned char*)ws;                     // 4 MB fp4, K-major
    float* ppos = (float*)(ws + (size_t)64 * KSTRIDE);           // NBLK*N floats (2 MB)
    float* pall = ppos + (size_t)NBLK * N_ROWS;                  // NBLK*N floats (2 MB)
    unsigned long long* acc = (unsigned long long*)(pall + (size_t)NBLK * N_ROWS);
    int* ghist = (int*)(acc + 4);                                // 64 ints

    // zero ticket/sum/cnt + histogram (graph-capture-safe async memset)
    hipMemsetAsync(acc, 0, 4 * sizeof(unsigned long long) + NUM_CLS * sizeof(int),
                   stream);
    norm_kernel<<<N_ROWS / 8, 256, 0, stream>>>(emb, xqT, labels, ghist);
    simloss_kernel<<<GRID_K2, 256, 0, stream>>>(xqT, labels, ppos, pall);
    finalize_kernel<<<NBLK, 256, 0, stream>>>(labels, ppos, pall, ghist, acc, out);
}

// Round 14
// 91.045 us; speedup vs baseline: 1.2746x; 1.1181x over previous
//
#include <hip/hip_runtime.h>
#include <hip/hip_bf16.h>

#define N_ROWS 8192
#define H_DIM  1024
#define NUM_CLS 64
#define BM 128
#define BN 128
#define NBLK (N_ROWS / BM)               // 64 panels
#define KSTRIDE ((size_t)N_ROWS * 16)    // bytes per kchunk plane (131072)
#define SCALE_E8M0 0x79797979            // 121 -> 2^-6 per operand (x stored *64)
#define FIXSCALE 16777216.0              // 2^24 fixed-point for deterministic sum
#define GRID_K2 (8 * 264)                // 8 XCD slots x 264 (32 no-op blocks)

typedef float f32x4 __attribute__((ext_vector_type(4)));
typedef int   i32x4 __attribute__((ext_vector_type(4)));
typedef int   i32x8 __attribute__((ext_vector_type(8)));

__device__ __forceinline__ float fast_exp2(float x) {
    float r;
    asm("v_exp_f32 %0, %1" : "=v"(r) : "v"(x));
    return r;
}

// e2m1 encode of f (pre-scaled): codes 0..7 = {0,.5,1,1.5,2,3,4,6}, bit3 = sign
__device__ __forceinline__ unsigned enc_fp4(float f) {
    const float a = fabsf(f);
    unsigned c = (unsigned)(a > 0.25f) + (unsigned)(a > 0.75f) +
                 (unsigned)(a > 1.25f) + (unsigned)(a > 1.75f) +
                 (unsigned)(a > 2.5f)  + (unsigned)(a > 3.5f) +
                 (unsigned)(a > 5.0f);
    return c | ((__float_as_uint(f) >> 31) << 3);
}

// --- Kernel 1: row-normalize fp32 -> fp4 e2m1 (x*64), K-MAJOR layout ---
// 16 rows/block; LDS transpose so global writes are 256B-contiguous slabs.
// Also zeroes the finalize reducers (safe: stream-ordered before finalize).
__global__ __launch_bounds__(256) void norm_kernel(const float* __restrict__ in,
                                                   unsigned char* __restrict__ xqT,
                                                   unsigned long long* __restrict__ acc) {
    if (blockIdx.x == 0 && threadIdx.x < 4) acc[threadIdx.x] = 0ULL;
    __shared__ __align__(16) unsigned char lt[16 * 528];   // 528B row stride: pad
    const int tid  = threadIdx.x;
    const int wid  = tid >> 6, lane = tid & 63;
    const int r = lane >> 4, c = lane & 15;     // row-in-wave, 64-elem chunk
    const int lrow = wid * 4 + r;               // 0..15
    const int row  = blockIdx.x * 16 + lrow;
    const float4* src = reinterpret_cast<const float4*>(in + (size_t)row * H_DIM)
                        + c * 16;               // 64 contiguous elems per lane
    float4 v[16];
    float ss = 0.f;
#pragma unroll
    for (int i = 0; i < 16; ++i) {
        v[i] = src[i];
        ss += v[i].x * v[i].x + v[i].y * v[i].y + v[i].z * v[i].z + v[i].w * v[i].w;
    }
#pragma unroll
    for (int d = 1; d < 16; d <<= 1) ss += __shfl_xor(ss, d, 64);  // 16-lane row sum
    const float inv = 64.0f / fmaxf(sqrtf(ss), 1e-12f);
#pragma unroll
    for (int h = 0; h < 2; ++h) {               // kchunks 2c, 2c+1
        i32x4 dw;
#pragma unroll
        for (int j = 0; j < 4; ++j) {
            unsigned d = 0;
#pragma unroll
            for (int k = 0; k < 8; ++k) {
                const int e = j * 8 + k;        // elem 0..31 within kchunk
                const float f = ((const float*)&v[h * 8 + (e >> 2)])[e & 3] * inv;
                d |= enc_fp4(f) << (4 * k);
            }
            dw[j] = (int)d;
        }
        *reinterpret_cast<i32x4*>(&lt[lrow * 528 + (2 * c + h) * 16]) = dw;
    }
    __syncthreads();
    // write: 32 planes x (16 rows x 16B = 256B contiguous); 16 threads/plane
#pragma unroll
    for (int it = 0; it < 2; ++it) {
        const int p  = it * 16 + (tid >> 4);
        const int rr = tid & 15;
        *reinterpret_cast<i32x4*>(xqT + (size_t)p * KSTRIDE +
                                  (size_t)(blockIdx.x * 16 + rr) * 16) =
            *reinterpret_cast<const i32x4*>(&lt[rr * 528 + p * 16]);
    }
}

// 28 off-diagonal 8x8-panel super-tiles (a<b), packed a<<3|b, row-major
__device__ __constant__ unsigned char OFF_TBL[28] = {
    1, 2, 3, 4, 5, 6, 7,
    10, 11, 12, 13, 14, 15,
    19, 20, 21, 22, 23,
    28, 29, 30, 31,
    37, 38, 39,
    46, 47,
    55
};

// ---- Kernel 2: symmetric fused Gram + exp + masked row/col partials ----
// Wave-autonomous, barrier-free K-loop, direct global->VGPR fragments
// (K-major layout, L2-hot via super-tile XCD co-schedule), register
// pipeline 2 STEPS AHEAD (3 named buffer sets, static indices).
__global__ __launch_bounds__(256)
void simloss_kernel(const unsigned char* __restrict__ xqT, const int* __restrict__ labels,
                    float* __restrict__ ppos, float* __restrict__ pall) {
    __shared__ float sc[1024];            // 4 KB epilogue scratch only

    // ---- super-tile decode: xcd = blockIdx%8 owns a fixed tile list ----
    const int xcd = blockIdx.x & 7;
    const int n   = blockIdx.x >> 3;     // 0..263 within this XCD
    int I, J;
    if (xcd < 4) {                        // 4 off-diag tiles (256 blocks)
        if (n >= 256) return;
        const int t = OFF_TBL[xcd * 4 + (n >> 6)];
        I = (t >> 3) * 8 + ((n >> 3) & 7);
        J = (t & 7) * 8 + (n & 7);
    } else if (n < 192) {                 // 3 off-diag tiles
        const int t = OFF_TBL[16 + (xcd - 4) * 3 + (n >> 6)];
        I = (t >> 3) * 8 + ((n >> 3) & 7);
        J = (t & 7) * 8 + (n & 7);
    } else {                              // 2 diag tiles (36 blocks each)
        int n2 = n - 192;                 // 0..71
        const int D = (xcd - 4) * 2 + (n2 >= 36 ? 1 : 0);
        int t2 = (n2 >= 36) ? n2 - 36 : n2;
        int i = 0;
        while (t2 >= 8 - i) { t2 -= 8 - i; ++i; }
        I = D * 8 + i;
        J = D * 8 + i + t2;
    }
    const bool diag = (I == J);
    const int row0 = I * BM, col0 = J * BN;

    const int tid  = threadIdx.x;
    const int lane = tid & 63;
    const int wid  = tid >> 6;
    const int wr = wid >> 1, wc = wid & 1;
    const int l15 = lane & 15, lq = lane >> 4;

    f32x4 acc[4][4];
#pragma unroll
    for (int m = 0; m < 4; ++m)
#pragma unroll
        for (int n2 = 0; n2 < 4; ++n2) acc[m][n2] = (f32x4){0.f, 0.f, 0.f, 0.f};

    // fragment bases: lane (l15,lq) reads 16B at (row, kc = s*4+lq);
    // 16 consecutive l15 rows = 256B contiguous per lq group (coalesced)
    const unsigned char* Ap = xqT + (size_t)lq * KSTRIDE + (size_t)(row0 + wr * 64 + l15) * 16;
    const unsigned char* Bp = xqT + (size_t)lq * KSTRIDE + (size_t)(col0 + wc * 64 + l15) * 16;
    const i32x4 z4 = {0, 0, 0, 0};

#define LOADS(BUF, S)                                                          \
    do {                                                                       \
        _Pragma("unroll")                                                      \
        for (int m = 0; m < 4; ++m)                                            \
            A##BUF[m] = *reinterpret_cast<const i32x4*>(                       \
                Ap + (size_t)(S) * 4 * KSTRIDE + m * 256);                     \
        _Pragma("unroll")                                                      \
        for (int n2 = 0; n2 < 4; ++n2)                                         \
            B##BUF[n2] = *reinterpret_cast<const i32x4*>(                      \
                Bp + (size_t)(S) * 4 * KSTRIDE + n2 * 256);                    \
    } while (0)

#define MFMA_STEP(BUF)                                                         \
    do {                                                                       \
        __builtin_amdgcn_s_setprio(1);                                         \
        _Pragma("unroll")                                                      \
        for (int m = 0; m < 4; ++m) {                                          \
            const i32x8 a8 = __builtin_shufflevector(A##BUF[m], z4,            \
                                                     0, 1, 2, 3, 4, 5, 6, 7);  \
            _Pragma("unroll")                                                  \
            for (int n2 = 0; n2 < 4; ++n2) {                                   \
                const i32x8 b8 = __builtin_shufflevector(B##BUF[n2], z4,       \
                                                         0, 1, 2, 3, 4, 5, 6, 7); \
                acc[m][n2] = __builtin_amdgcn_mfma_scale_f32_16x16x128_f8f6f4( \
                    a8, b8, acc[m][n2], 4, 4, 0, SCALE_E8M0, 0, SCALE_E8M0);   \
            }                                                                  \
        }                                                                      \
        __builtin_amdgcn_s_setprio(0);                                         \
    } while (0)

    // 3 named register buffer sets, 2-steps-ahead prefetch, no barriers:
    // compiler-counted vmcnt keeps ~2 steps of loads in flight under MFMAs.
    i32x4 A0[4], B0[4], A1[4], B1[4], A2[4], B2[4];
    LOADS(0, 0);
    LOADS(1, 1);
    LOADS(2, 2);
    MFMA_STEP(0);          // s=0
    LOADS(0, 3);
    MFMA_STEP(1);          // s=1
    LOADS(1, 4);
    MFMA_STEP(2);          // s=2
    LOADS(2, 5);
    MFMA_STEP(0);          // s=3
    LOADS(0, 6);
    MFMA_STEP(1);          // s=4
    LOADS(1, 7);
    MFMA_STEP(2);          // s=5
    MFMA_STEP(0);          // s=6
    MFMA_STEP(1);          // s=7
#undef LOADS
#undef MFMA_STEP

    // ---- epilogue: exp + masked row sums AND column sums ----
    int lab_r[16];
#pragma unroll
    for (int m = 0; m < 4; ++m)
#pragma unroll
        for (int r = 0; r < 4; ++r)
            lab_r[m * 4 + r] = labels[row0 + wr * 64 + m * 16 + lq * 4 + r];

    float rs_pos[16], rs_all[16];
#pragma unroll
    for (int i = 0; i < 16; ++i) { rs_pos[i] = 0.f; rs_all[i] = 0.f; }
    float cs_pos[4], cs_all[4];
#pragma unroll
    for (int n2 = 0; n2 < 4; ++n2) { cs_pos[n2] = 0.f; cs_all[n2] = 0.f; }

#pragma unroll
    for (int n2 = 0; n2 < 4; ++n2) {
        const int colg = col0 + wc * 64 + n2 * 16 + l15;
        const int lab_c = labels[colg];
#pragma unroll
        for (int m = 0; m < 4; ++m) {
#pragma unroll
            for (int r = 0; r < 4; ++r) {
                const int rowg = row0 + wr * 64 + m * 16 + lq * 4 + r;
                const float e = fast_exp2(acc[m][n2][r] * 14.4269504088896340736f);
                const bool self = (rowg == colg);       // only possible when diag
                const bool pos  = (lab_c == lab_r[m * 4 + r]) && !self;
                const float ea = self ? 0.f : e;
                const float ep = pos ? e : 0.f;
                rs_all[m * 4 + r] += ea;
                rs_pos[m * 4 + r] += ep;
                cs_all[n2] += ea;
                cs_pos[n2] += ep;
            }
        }
    }

#pragma unroll
    for (int i = 0; i < 16; ++i) {
#pragma unroll
        for (int d = 1; d < 16; d <<= 1) {
            rs_pos[i] += __shfl_xor(rs_pos[i], d, 64);
            rs_all[i] += __shfl_xor(rs_all[i], d, 64);
        }
    }
#pragma unroll
    for (int n2 = 0; n2 < 4; ++n2) {
#pragma unroll
        for (int d = 16; d < 64; d <<= 1) {
            cs_pos[n2] += __shfl_xor(cs_pos[n2], d, 64);
            cs_all[n2] += __shfl_xor(cs_all[n2], d, 64);
        }
    }

    float* rowpos = sc;                    // [2][128] indexed [wc][localrow]
    float* rowall = sc + 256;
    float* colpos = sc + 512;              // [2][128] indexed [wr][localcol]
    float* colall = sc + 768;
    if (l15 == 0) {
#pragma unroll
        for (int i = 0; i < 16; ++i) {
            const int m = i >> 2, r = i & 3;
            const int lr = wr * 64 + m * 16 + lq * 4 + r;
            rowpos[wc * 128 + lr] = rs_pos[i];
            rowall[wc * 128 + lr] = rs_all[i];
        }
    }
    if (lq == 0 && !diag) {
#pragma unroll
        for (int n2 = 0; n2 < 4; ++n2) {
            const int lc = wc * 64 + n2 * 16 + l15;
            colpos[wr * 128 + lc] = cs_pos[n2];
            colall[wr * 128 + lc] = cs_all[n2];
        }
    }
    __syncthreads();

    // partial-slot scheme: row-side -> slot J, col-side -> slot I (exactly once)
    if (tid < 128) {
        const float rp = rowpos[tid] + rowpos[128 + tid];
        const float ra = rowall[tid] + rowall[128 + tid];
        ppos[(size_t)J * N_ROWS + row0 + tid] = rp;
        pall[(size_t)J * N_ROWS + row0 + tid] = ra;
    } else if (!diag) {
        const int t2 = tid - 128;
        const float cp = colpos[t2] + colpos[128 + t2];
        const float ca = colall[t2] + colall[128 + t2];
        ppos[(size_t)I * N_ROWS + col0 + t2] = cp;
        pall[(size_t)I * N_ROWS + col0 + t2] = ca;
    }
}

// ---- Kernel 3: fused finalize (LDS hist rescan + int64 fixed-point ticket) ----
__global__ __launch_bounds__(256)
void finalize_kernel(const int* __restrict__ labels, const float* __restrict__ ppos,
                     const float* __restrict__ pall, unsigned long long* __restrict__ acc,
                     float* __restrict__ out) {
    __shared__ int hist[NUM_CLS];
    __shared__ float sred[4];
    __shared__ int scnt[4];
    const int tid = threadIdx.x;
    if (tid < NUM_CLS) hist[tid] = 0;
    __syncthreads();
    for (int i = tid; i < N_ROWS; i += 256) atomicAdd(&hist[labels[i]], 1);
    __syncthreads();

    float lsum = 0.f;
    int vcnt = 0;
    if (tid < 128) {
        const int i = blockIdx.x * 128 + tid;
        float p = 0.f, a = 0.f;
#pragma unroll
        for (int s = 0; s < NBLK; ++s) {
            p += ppos[(size_t)s * N_ROWS + i];
            a += pall[(size_t)s * N_ROWS + i];
        }
        const int cnt = hist[labels[i]] - 1;
        if (cnt > 0) {
            lsum = logf(a) - logf(p) + logf((float)cnt);   // >= 0 structurally
            vcnt = 1;
        }
    }
    const int lane = tid & 63, wid = tid >> 6;
#pragma unroll
    for (int d = 1; d < 64; d <<= 1) {
        lsum += __shfl_xor(lsum, d, 64);
        vcnt += __shfl_xor(vcnt, d, 64);
    }
    if (lane == 0) { sred[wid] = lsum; scnt[wid] = vcnt; }
    __syncthreads();
    if (tid == 0) {
        const double bs = (double)(sred[0] + sred[1] + sred[2] + sred[3]);
        const unsigned long long S = (unsigned long long)(bs * FIXSCALE + 0.5);
        const unsigned long long C = (unsigned long long)(scnt[0] + scnt[1] + scnt[2] + scnt[3]);
        atomicAdd(&acc[1], S);
        atomicAdd(&acc[2], C);
        __threadfence();
        const unsigned long long tk = atomicAdd(&acc[0], 1ULL);
        if (tk == (unsigned long long)(NBLK - 1)) {
            volatile unsigned long long* va = acc;
            const double St = (double)va[1];
            const double Ct = (double)va[2];
            out[0] = (float)(St / FIXSCALE / Ct);
        }
    }
}

extern "C" void kernel_launch(void* const* d_in, const int* in_sizes, int n_in,
                              void* d_out, int out_size, void* d_ws, size_t ws_size,
                              hipStream_t stream) {
    const float* emb   = (const float*)d_in[0];
    const int* labels  = (const int*)d_in[1];
    float* out         = (float*)d_out;
    char* ws           = (char*)d_ws;

    unsigned char* xqT = (unsigned char*)ws;                     // 4 MB fp4, K-major
    float* ppos = (float*)(ws + (size_t)64 * KSTRIDE);           // NBLK*N floats (2 MB)
    float* pall = ppos + (size_t)NBLK * N_ROWS;                  // NBLK*N floats (2 MB)
    unsigned long long* acc = (unsigned long long*)(pall + (size_t)NBLK * N_ROWS);

    norm_kernel<<<N_ROWS / 16, 256, 0, stream>>>(emb, xqT, acc);
    simloss_kernel<<<GRID_K2, 256, 0, stream>>>(xqT, labels, ppos, pall);
    finalize_kernel<<<NBLK, 256, 0, stream>>>(labels, ppos, pall, acc, out);
}

// Round 15
// 73.301 us; speedup vs baseline: 1.5832x; 1.2421x over previous
//
#include <hip/hip_runtime.h>
#include <hip/hip_bf16.h>

#define N_ROWS 8192
#define H_DIM  1024
#define NUM_CLS 64
#define BM 128
#define BN 128
#define NBLK (N_ROWS / BM)               // 64 panels
#define KSTRIDE ((size_t)N_ROWS * 16)    // bytes per kchunk plane (131072)
#define SCALE_E8M0 0x79797979            // 121 -> 2^-6 per operand (x stored *64)
#define FIX2 1048576.0f                  // 2^20 row-accumulator fixed point
#define FIXSCALE 16777216.0              // 2^24 final-sum fixed point
#define GRID_K2 (8 * 264)                // 8 XCD slots x 264 (32 no-op blocks)
#define NFIN 32                          // finalize blocks

typedef float f32x4 __attribute__((ext_vector_type(4)));
typedef int   i32x4 __attribute__((ext_vector_type(4)));
typedef int   i32x8 __attribute__((ext_vector_type(8)));
typedef unsigned long long u64;

__device__ __forceinline__ float fast_exp2(float x) {
    float r;
    asm("v_exp_f32 %0, %1" : "=v"(r) : "v"(x));
    return r;
}

// e2m1 encode of f (pre-scaled): codes 0..7 = {0,.5,1,1.5,2,3,4,6}, bit3 = sign
__device__ __forceinline__ unsigned enc_fp4(float f) {
    const float a = fabsf(f);
    unsigned c = (unsigned)(a > 0.25f) + (unsigned)(a > 0.75f) +
                 (unsigned)(a > 1.25f) + (unsigned)(a > 1.75f) +
                 (unsigned)(a > 2.5f)  + (unsigned)(a > 3.5f) +
                 (unsigned)(a > 5.0f);
    return c | ((__float_as_uint(f) >> 31) << 3);
}

// --- Kernel 1: row-normalize fp32 -> fp4 e2m1 (x*64), K-MAJOR layout ---
// 16 rows/block; LDS transpose -> 256B-contiguous global writes.
// Also: zeroes this block's row-accumulators (stream-ordered before simloss)
// and histograms this block's labels (global int atomics = deterministic).
__global__ __launch_bounds__(256) void norm_kernel(const float* __restrict__ in,
                                                   unsigned char* __restrict__ xqT,
                                                   const int* __restrict__ labels,
                                                   int* __restrict__ ghist,
                                                   u64* __restrict__ rsum_pos,
                                                   u64* __restrict__ rsum_all) {
    if (threadIdx.x < 16) {
        const int r0 = blockIdx.x * 16 + threadIdx.x;
        rsum_pos[r0] = 0ULL;
        rsum_all[r0] = 0ULL;
        atomicAdd(&ghist[labels[r0]], 1);
    }
    __shared__ __align__(16) unsigned char lt[16 * 528];   // 528B row stride: pad
    const int tid  = threadIdx.x;
    const int wid  = tid >> 6, lane = tid & 63;
    const int r = lane >> 4, c = lane & 15;     // row-in-wave, 64-elem chunk
    const int lrow = wid * 4 + r;               // 0..15
    const int row  = blockIdx.x * 16 + lrow;
    const float4* src = reinterpret_cast<const float4*>(in + (size_t)row * H_DIM)
                        + c * 16;               // 64 contiguous elems per lane
    float4 v[16];
    float ss = 0.f;
#pragma unroll
    for (int i = 0; i < 16; ++i) {
        v[i] = src[i];
        ss += v[i].x * v[i].x + v[i].y * v[i].y + v[i].z * v[i].z + v[i].w * v[i].w;
    }
#pragma unroll
    for (int d = 1; d < 16; d <<= 1) ss += __shfl_xor(ss, d, 64);  // 16-lane row sum
    const float inv = 64.0f / fmaxf(sqrtf(ss), 1e-12f);
#pragma unroll
    for (int h = 0; h < 2; ++h) {               // kchunks 2c, 2c+1
        i32x4 dw;
#pragma unroll
        for (int j = 0; j < 4; ++j) {
            unsigned d = 0;
#pragma unroll
            for (int k = 0; k < 8; ++k) {
                const int e = j * 8 + k;        // elem 0..31 within kchunk
                const float f = ((const float*)&v[h * 8 + (e >> 2)])[e & 3] * inv;
                d |= enc_fp4(f) << (4 * k);
            }
            dw[j] = (int)d;
        }
        *reinterpret_cast<i32x4*>(&lt[lrow * 528 + (2 * c + h) * 16]) = dw;
    }
    __syncthreads();
    // write: 32 planes x (16 rows x 16B = 256B contiguous); 16 threads/plane
#pragma unroll
    for (int it = 0; it < 2; ++it) {
        const int p  = it * 16 + (tid >> 4);
        const int rr = tid & 15;
        *reinterpret_cast<i32x4*>(xqT + (size_t)p * KSTRIDE +
                                  (size_t)(blockIdx.x * 16 + rr) * 16) =
            *reinterpret_cast<const i32x4*>(&lt[rr * 528 + p * 16]);
    }
}

// 28 off-diagonal 8x8-panel super-tiles (a<b), packed a<<3|b, row-major
__device__ __constant__ unsigned char OFF_TBL[28] = {
    1, 2, 3, 4, 5, 6, 7,
    10, 11, 12, 13, 14, 15,
    19, 20, 21, 22, 23,
    28, 29, 30, 31,
    37, 38, 39,
    46, 47,
    55
};

// ---- Kernel 2: symmetric fused Gram + exp + masked row/col partials ----
// Wave-autonomous barrier-free K-loop, direct global->VGPR fragments
// (K-major, L2-hot via super-tile XCD co-schedule), register pipeline
// 2 steps ahead. Partials -> DETERMINISTIC int64 fixed-point atomics.
__global__ __launch_bounds__(256)
void simloss_kernel(const unsigned char* __restrict__ xqT, const int* __restrict__ labels,
                    u64* __restrict__ rsum_pos, u64* __restrict__ rsum_all) {
    __shared__ float sc[1024];            // 4 KB epilogue scratch only

    // ---- super-tile decode: xcd = blockIdx%8 owns a fixed tile list ----
    const int xcd = blockIdx.x & 7;
    const int n   = blockIdx.x >> 3;     // 0..263 within this XCD
    int I, J;
    if (xcd < 4) {                        // 4 off-diag tiles (256 blocks)
        if (n >= 256) return;
        const int t = OFF_TBL[xcd * 4 + (n >> 6)];
        I = (t >> 3) * 8 + ((n >> 3) & 7);
        J = (t & 7) * 8 + (n & 7);
    } else if (n < 192) {                 // 3 off-diag tiles
        const int t = OFF_TBL[16 + (xcd - 4) * 3 + (n >> 6)];
        I = (t >> 3) * 8 + ((n >> 3) & 7);
        J = (t & 7) * 8 + (n & 7);
    } else {                              // 2 diag tiles (36 blocks each)
        int n2 = n - 192;                 // 0..71
        const int D = (xcd - 4) * 2 + (n2 >= 36 ? 1 : 0);
        int t2 = (n2 >= 36) ? n2 - 36 : n2;
        int i = 0;
        while (t2 >= 8 - i) { t2 -= 8 - i; ++i; }
        I = D * 8 + i;
        J = D * 8 + i + t2;
    }
    const bool diag = (I == J);
    const int row0 = I * BM, col0 = J * BN;

    const int tid  = threadIdx.x;
    const int lane = tid & 63;
    const int wid  = tid >> 6;
    const int wr = wid >> 1, wc = wid & 1;
    const int l15 = lane & 15, lq = lane >> 4;

    f32x4 acc[4][4];
#pragma unroll
    for (int m = 0; m < 4; ++m)
#pragma unroll
        for (int n2 = 0; n2 < 4; ++n2) acc[m][n2] = (f32x4){0.f, 0.f, 0.f, 0.f};

    // fragment bases: lane (l15,lq) reads 16B at (row, kc = s*4+lq);
    // 16 consecutive l15 rows = 256B contiguous per lq group (coalesced)
    const unsigned char* Ap = xqT + (size_t)lq * KSTRIDE + (size_t)(row0 + wr * 64 + l15) * 16;
    const unsigned char* Bp = xqT + (size_t)lq * KSTRIDE + (size_t)(col0 + wc * 64 + l15) * 16;
    const i32x4 z4 = {0, 0, 0, 0};

#define LOADS(BUF, S)                                                          \
    do {                                                                       \
        _Pragma("unroll")                                                      \
        for (int m = 0; m < 4; ++m)                                            \
            A##BUF[m] = *reinterpret_cast<const i32x4*>(                       \
                Ap + (size_t)(S) * 4 * KSTRIDE + m * 256);                     \
        _Pragma("unroll")                                                      \
        for (int n2 = 0; n2 < 4; ++n2)                                         \
            B##BUF[n2] = *reinterpret_cast<const i32x4*>(                      \
                Bp + (size_t)(S) * 4 * KSTRIDE + n2 * 256);                    \
    } while (0)

#define MFMA_STEP(BUF)                                                         \
    do {                                                                       \
        __builtin_amdgcn_s_setprio(1);                                         \
        _Pragma("unroll")                                                      \
        for (int m = 0; m < 4; ++m) {                                          \
            const i32x8 a8 = __builtin_shufflevector(A##BUF[m], z4,            \
                                                     0, 1, 2, 3, 4, 5, 6, 7);  \
            _Pragma("unroll")                                                  \
            for (int n2 = 0; n2 < 4; ++n2) {                                   \
                const i32x8 b8 = __builtin_shufflevector(B##BUF[n2], z4,       \
                                                         0, 1, 2, 3, 4, 5, 6, 7); \
                acc[m][n2] = __builtin_amdgcn_mfma_scale_f32_16x16x128_f8f6f4( \
                    a8, b8, acc[m][n2], 4, 4, 0, SCALE_E8M0, 0, SCALE_E8M0);   \
            }                                                                  \
        }                                                                      \
        __builtin_amdgcn_s_setprio(0);                                         \
    } while (0)

    // 3 named register buffer sets, 2-steps-ahead prefetch, no barriers
    i32x4 A0[4], B0[4], A1[4], B1[4], A2[4], B2[4];
    LOADS(0, 0);
    LOADS(1, 1);
    LOADS(2, 2);
    MFMA_STEP(0);          // s=0
    LOADS(0, 3);
    MFMA_STEP(1);          // s=1
    LOADS(1, 4);
    MFMA_STEP(2);          // s=2
    LOADS(2, 5);
    MFMA_STEP(0);          // s=3
    LOADS(0, 6);
    MFMA_STEP(1);          // s=4
    LOADS(1, 7);
    MFMA_STEP(2);          // s=5
    MFMA_STEP(0);          // s=6
    MFMA_STEP(1);          // s=7
#undef LOADS
#undef MFMA_STEP

    // ---- epilogue: exp + masked row sums AND column sums ----
    int lab_r[16];
#pragma unroll
    for (int m = 0; m < 4; ++m)
#pragma unroll
        for (int r = 0; r < 4; ++r)
            lab_r[m * 4 + r] = labels[row0 + wr * 64 + m * 16 + lq * 4 + r];

    float rs_pos[16], rs_all[16];
#pragma unroll
    for (int i = 0; i < 16; ++i) { rs_pos[i] = 0.f; rs_all[i] = 0.f; }
    float cs_pos[4], cs_all[4];
#pragma unroll
    for (int n2 = 0; n2 < 4; ++n2) { cs_pos[n2] = 0.f; cs_all[n2] = 0.f; }

#pragma unroll
    for (int n2 = 0; n2 < 4; ++n2) {
        const int colg = col0 + wc * 64 + n2 * 16 + l15;
        const int lab_c = labels[colg];
#pragma unroll
        for (int m = 0; m < 4; ++m) {
#pragma unroll
            for (int r = 0; r < 4; ++r) {
                const int rowg = row0 + wr * 64 + m * 16 + lq * 4 + r;
                const float e = fast_exp2(acc[m][n2][r] * 14.4269504088896340736f);
                const bool self = (rowg == colg);       // only possible when diag
                const bool pos  = (lab_c == lab_r[m * 4 + r]) && !self;
                const float ea = self ? 0.f : e;
                const float ep = pos ? e : 0.f;
                rs_all[m * 4 + r] += ea;
                rs_pos[m * 4 + r] += ep;
                cs_all[n2] += ea;
                cs_pos[n2] += ep;
            }
        }
    }

#pragma unroll
    for (int i = 0; i < 16; ++i) {
#pragma unroll
        for (int d = 1; d < 16; d <<= 1) {
            rs_pos[i] += __shfl_xor(rs_pos[i], d, 64);
            rs_all[i] += __shfl_xor(rs_all[i], d, 64);
        }
    }
#pragma unroll
    for (int n2 = 0; n2 < 4; ++n2) {
#pragma unroll
        for (int d = 16; d < 64; d <<= 1) {
            cs_pos[n2] += __shfl_xor(cs_pos[n2], d, 64);
            cs_all[n2] += __shfl_xor(cs_all[n2], d, 64);
        }
    }

    float* rowpos = sc;                    // [2][128] indexed [wc][localrow]
    float* rowall = sc + 256;
    float* colpos = sc + 512;              // [2][128] indexed [wr][localcol]
    float* colall = sc + 768;
    if (l15 == 0) {
#pragma unroll
        for (int i = 0; i < 16; ++i) {
            const int m = i >> 2, r = i & 3;
            const int lr = wr * 64 + m * 16 + lq * 4 + r;
            rowpos[wc * 128 + lr] = rs_pos[i];
            rowall[wc * 128 + lr] = rs_all[i];
        }
    }
    if (lq == 0 && !diag) {
#pragma unroll
        for (int n2 = 0; n2 < 4; ++n2) {
            const int lc = wc * 64 + n2 * 16 + l15;
            colpos[wr * 128 + lc] = cs_pos[n2];
            colall[wr * 128 + lc] = cs_all[n2];
        }
    }
    __syncthreads();

    // deterministic int64 fixed-point row accumulation (adds are
    // commutative-exact -> order-independent across blocks/replays)
    if (tid < 128) {
        const float rp = rowpos[tid] + rowpos[128 + tid];
        const float ra = rowall[tid] + rowall[128 + tid];
        atomicAdd(&rsum_pos[row0 + tid], (u64)(rp * FIX2 + 0.5f));
        atomicAdd(&rsum_all[row0 + tid], (u64)(ra * FIX2 + 0.5f));
    } else if (!diag) {
        const int t2 = tid - 128;
        const float cp = colpos[t2] + colpos[128 + t2];
        const float ca = colall[t2] + colall[128 + t2];
        atomicAdd(&rsum_pos[col0 + t2], (u64)(cp * FIX2 + 0.5f));
        atomicAdd(&rsum_all[col0 + t2], (u64)(ca * FIX2 + 0.5f));
    }
}

// ---- Kernel 3: lean finalize: 1 row/thread, coalesced u64 reads ----
__global__ __launch_bounds__(256)
void finalize_kernel(const int* __restrict__ labels, const u64* __restrict__ rsum_pos,
                     const u64* __restrict__ rsum_all, const int* __restrict__ ghist,
                     u64* __restrict__ acc, float* __restrict__ out) {
    __shared__ float sred[4];
    __shared__ int scnt[4];
    const int tid = threadIdx.x;
    const int i = blockIdx.x * 256 + tid;

    const u64 rp = rsum_pos[i];
    const u64 ra = rsum_all[i];
    const int cnt = ghist[labels[i]] - 1;
    float lsum = 0.f;
    int vcnt = 0;
    if (cnt > 0) {
        const float p = fmaxf((float)((double)rp / (double)FIX2), 1e-30f);
        const float a = (float)((double)ra / (double)FIX2);
        lsum = logf(a) - logf(p) + logf((float)cnt);
        vcnt = 1;
    }
    const int lane = tid & 63, wid = tid >> 6;
#pragma unroll
    for (int d = 1; d < 64; d <<= 1) {
        lsum += __shfl_xor(lsum, d, 64);
        vcnt += __shfl_xor(vcnt, d, 64);
    }
    if (lane == 0) { sred[wid] = lsum; scnt[wid] = vcnt; }
    __syncthreads();
    if (tid == 0) {
        const double bs = (double)(sred[0] + sred[1] + sred[2] + sred[3]);
        const u64 S = (u64)(bs * FIXSCALE + 0.5);
        const u64 C = (u64)(scnt[0] + scnt[1] + scnt[2] + scnt[3]);
        atomicAdd(&acc[1], S);
        atomicAdd(&acc[2], C);
        __threadfence();
        const u64 tk = atomicAdd(&acc[0], 1ULL);
        if (tk == (u64)(NFIN - 1)) {
            volatile u64* va = acc;
            const double St = (double)va[1];
            const double Ct = (double)va[2];
            out[0] = (float)(St / FIXSCALE / Ct);
        }
    }
}

extern "C" void kernel_launch(void* const* d_in, const int* in_sizes, int n_in,
                              void* d_out, int out_size, void* d_ws, size_t ws_size,
                              hipStream_t stream) {
    const float* emb   = (const float*)d_in[0];
    const int* labels  = (const int*)d_in[1];
    float* out         = (float*)d_out;
    char* ws           = (char*)d_ws;

    unsigned char* xqT = (unsigned char*)ws;                     // 4 MB fp4, K-major (32 planes)
    u64* rsum_pos = (u64*)(ws + (size_t)32 * KSTRIDE);           // 64 KB
    u64* rsum_all = rsum_pos + N_ROWS;                           // 64 KB
    u64* acc      = rsum_all + N_ROWS;                           // 32 B
    int* ghist    = (int*)(acc + 4);                             // 256 B

    hipMemsetAsync(acc, 0, 4 * sizeof(u64) + NUM_CLS * sizeof(int), stream);
    norm_kernel<<<N_ROWS / 16, 256, 0, stream>>>(emb, xqT, labels, ghist,
                                                 rsum_pos, rsum_all);
    simloss_kernel<<<GRID_K2, 256, 0, stream>>>(xqT, labels, rsum_pos, rsum_all);
    finalize_kernel<<<NFIN, 256, 0, stream>>>(labels, rsum_pos, rsum_all, ghist,
                                              acc, out);
}

// Round 16
// 64.619 us; speedup vs baseline: 1.7959x; 1.1343x over previous
//
#include <hip/hip_runtime.h>
#include <hip/hip_bf16.h>

#define N_ROWS 8192
#define H_DIM  1024
#define NUM_CLS 64
#define BM 128
#define BN 128
#define NBLK (N_ROWS / BM)               // 64 panels
#define KSTRIDE ((size_t)N_ROWS * 16)    // bytes per kchunk plane (131072)
#define SCALE_E8M0 0x79797979            // 121 -> 2^-6 per operand (x stored *64)
#define FIX2 1048576.0f                  // 2^20 row-accumulator fixed point
#define FIXSCALE 16777216.0              // 2^24 final-sum fixed point
#define GRID_K2 (8 * 264)                // 8 XCD slots x 264 (32 no-op blocks)
#define NFIN 32                          // finalize blocks

typedef float f32x4 __attribute__((ext_vector_type(4)));
typedef int   i32x4 __attribute__((ext_vector_type(4)));
typedef int   i32x8 __attribute__((ext_vector_type(8)));
typedef unsigned long long u64;

__device__ __forceinline__ float fast_exp2(float x) {
    float r;
    asm("v_exp_f32 %0, %1" : "=v"(r) : "v"(x));
    return r;
}

// e2m1 encode of f (pre-scaled): codes 0..7 = {0,.5,1,1.5,2,3,4,6}, bit3 = sign
__device__ __forceinline__ unsigned enc_fp4(float f) {
    const float a = fabsf(f);
    unsigned c = (unsigned)(a > 0.25f) + (unsigned)(a > 0.75f) +
                 (unsigned)(a > 1.25f) + (unsigned)(a > 1.75f) +
                 (unsigned)(a > 2.5f)  + (unsigned)(a > 3.5f) +
                 (unsigned)(a > 5.0f);
    return c | ((__float_as_uint(f) >> 31) << 3);
}

// --- Kernel 1: row-normalize fp32 -> fp4 e2m1 (x*64), K-MAJOR layout ---
// 16 rows/block; LDS transpose -> 256B-contiguous global writes.
// Zeroes this block's row-accumulators and (block 0) the finalize reducers.
__global__ __launch_bounds__(256) void norm_kernel(const float* __restrict__ in,
                                                   unsigned char* __restrict__ xqT,
                                                   u64* __restrict__ rsum_pos,
                                                   u64* __restrict__ rsum_all,
                                                   u64* __restrict__ acc) {
    if (blockIdx.x == 0 && threadIdx.x < 4) acc[threadIdx.x] = 0ULL;
    if (threadIdx.x < 16) {
        const int r0 = blockIdx.x * 16 + threadIdx.x;
        rsum_pos[r0] = 0ULL;
        rsum_all[r0] = 0ULL;
    }
    __shared__ __align__(16) unsigned char lt[16 * 528];   // 528B row stride: pad
    const int tid  = threadIdx.x;
    const int wid  = tid >> 6, lane = tid & 63;
    const int r = lane >> 4, c = lane & 15;     // row-in-wave, 64-elem chunk
    const int lrow = wid * 4 + r;               // 0..15
    const int row  = blockIdx.x * 16 + lrow;
    const float4* src = reinterpret_cast<const float4*>(in + (size_t)row * H_DIM)
                        + c * 16;               // 64 contiguous elems per lane
    float4 v[16];
    float ss = 0.f;
#pragma unroll
    for (int i = 0; i < 16; ++i) {
        v[i] = src[i];
        ss += v[i].x * v[i].x + v[i].y * v[i].y + v[i].z * v[i].z + v[i].w * v[i].w;
    }
#pragma unroll
    for (int d = 1; d < 16; d <<= 1) ss += __shfl_xor(ss, d, 64);  // 16-lane row sum
    const float inv = 64.0f / fmaxf(sqrtf(ss), 1e-12f);
#pragma unroll
    for (int h = 0; h < 2; ++h) {               // kchunks 2c, 2c+1
        i32x4 dw;
#pragma unroll
        for (int j = 0; j < 4; ++j) {
            unsigned d = 0;
#pragma unroll
            for (int k = 0; k < 8; ++k) {
                const int e = j * 8 + k;        // elem 0..31 within kchunk
                const float f = ((const float*)&v[h * 8 + (e >> 2)])[e & 3] * inv;
                d |= enc_fp4(f) << (4 * k);
            }
            dw[j] = (int)d;
        }
        *reinterpret_cast<i32x4*>(&lt[lrow * 528 + (2 * c + h) * 16]) = dw;
    }
    __syncthreads();
    // write: 32 planes x (16 rows x 16B = 256B contiguous); 16 threads/plane
#pragma unroll
    for (int it = 0; it < 2; ++it) {
        const int p  = it * 16 + (tid >> 4);
        const int rr = tid & 15;
        *reinterpret_cast<i32x4*>(xqT + (size_t)p * KSTRIDE +
                                  (size_t)(blockIdx.x * 16 + rr) * 16) =
            *reinterpret_cast<const i32x4*>(&lt[rr * 528 + p * 16]);
    }
}

// 28 off-diagonal 8x8-panel super-tiles (a<b), packed a<<3|b, row-major
__device__ __constant__ unsigned char OFF_TBL[28] = {
    1, 2, 3, 4, 5, 6, 7,
    10, 11, 12, 13, 14, 15,
    19, 20, 21, 22, 23,
    28, 29, 30, 31,
    37, 38, 39,
    46, 47,
    55
};

// ---- Kernel 2: symmetric fused Gram + exp + masked row/col partials ----
// Wave-autonomous barrier-free K-loop, direct global->VGPR fragments
// (K-major, L2-hot via super-tile XCD co-schedule). R13-proven 1-ahead
// 2-set register pipeline; operand tuples built ONCE per step with
// UNDEF upper half (fp4 MFMA reads only v[0:3] of each 8-reg operand).
__global__ __launch_bounds__(256)
void simloss_kernel(const unsigned char* __restrict__ xqT, const int* __restrict__ labels,
                    u64* __restrict__ rsum_pos, u64* __restrict__ rsum_all) {
    __shared__ float sc[1024];            // 4 KB epilogue scratch only

    // ---- super-tile decode: xcd = blockIdx%8 owns a fixed tile list ----
    const int xcd = blockIdx.x & 7;
    const int n   = blockIdx.x >> 3;     // 0..263 within this XCD
    int I, J;
    if (xcd < 4) {                        // 4 off-diag tiles (256 blocks)
        if (n >= 256) return;
        const int t = OFF_TBL[xcd * 4 + (n >> 6)];
        I = (t >> 3) * 8 + ((n >> 3) & 7);
        J = (t & 7) * 8 + (n & 7);
    } else if (n < 192) {                 // 3 off-diag tiles
        const int t = OFF_TBL[16 + (xcd - 4) * 3 + (n >> 6)];
        I = (t >> 3) * 8 + ((n >> 3) & 7);
        J = (t & 7) * 8 + (n & 7);
    } else {                              // 2 diag tiles (36 blocks each)
        int n2 = n - 192;                 // 0..71
        const int D = (xcd - 4) * 2 + (n2 >= 36 ? 1 : 0);
        int t2 = (n2 >= 36) ? n2 - 36 : n2;
        int i = 0;
        while (t2 >= 8 - i) { t2 -= 8 - i; ++i; }
        I = D * 8 + i;
        J = D * 8 + i + t2;
    }
    const bool diag = (I == J);
    const int row0 = I * BM, col0 = J * BN;

    const int tid  = threadIdx.x;
    const int lane = tid & 63;
    const int wid  = tid >> 6;
    const int wr = wid >> 1, wc = wid & 1;
    const int l15 = lane & 15, lq = lane >> 4;

    f32x4 acc[4][4];
#pragma unroll
    for (int m = 0; m < 4; ++m)
#pragma unroll
        for (int n2 = 0; n2 < 4; ++n2) acc[m][n2] = (f32x4){0.f, 0.f, 0.f, 0.f};

    // fragment bases: lane (l15,lq) reads 16B at (row, kc = s*4+lq);
    // 16 consecutive l15 rows = 256B contiguous per lq group (coalesced)
    const unsigned char* Ap = xqT + (size_t)lq * KSTRIDE + (size_t)(row0 + wr * 64 + l15) * 16;
    const unsigned char* Bp = xqT + (size_t)lq * KSTRIDE + (size_t)(col0 + wc * 64 + l15) * 16;

#define LOADS(BUF, S)                                                          \
    do {                                                                       \
        _Pragma("unroll")                                                      \
        for (int m = 0; m < 4; ++m)                                            \
            A##BUF[m] = *reinterpret_cast<const i32x4*>(                       \
                Ap + (size_t)(S) * 4 * KSTRIDE + m * 256);                     \
        _Pragma("unroll")                                                      \
        for (int n2 = 0; n2 < 4; ++n2)                                         \
            B##BUF[n2] = *reinterpret_cast<const i32x4*>(                      \
                Bp + (size_t)(S) * 4 * KSTRIDE + n2 * 256);                    \
    } while (0)

    // low 4 regs = data, upper 4 = UNDEF (fp4 mfma ignores them -> no movs)
#define BUILD8(dst, src) (dst) = __builtin_shufflevector((src), (src),         \
                                                         0, 1, 2, 3, -1, -1, -1, -1)

#define STEP(CUR, NXT, S, LAST)                                                \
    do {                                                                       \
        if (!(LAST)) LOADS(NXT, (S) + 1);                                      \
        i32x8 b80, b81, b82, b83;                                              \
        BUILD8(b80, B##CUR[0]); BUILD8(b81, B##CUR[1]);                        \
        BUILD8(b82, B##CUR[2]); BUILD8(b83, B##CUR[3]);                        \
        __builtin_amdgcn_s_setprio(1);                                         \
        _Pragma("unroll")                                                      \
        for (int m = 0; m < 4; ++m) {                                          \
            i32x8 a8;                                                          \
            BUILD8(a8, A##CUR[m]);                                             \
            acc[m][0] = __builtin_amdgcn_mfma_scale_f32_16x16x128_f8f6f4(      \
                a8, b80, acc[m][0], 4, 4, 0, SCALE_E8M0, 0, SCALE_E8M0);       \
            acc[m][1] = __builtin_amdgcn_mfma_scale_f32_16x16x128_f8f6f4(      \
                a8, b81, acc[m][1], 4, 4, 0, SCALE_E8M0, 0, SCALE_E8M0);       \
            acc[m][2] = __builtin_amdgcn_mfma_scale_f32_16x16x128_f8f6f4(      \
                a8, b82, acc[m][2], 4, 4, 0, SCALE_E8M0, 0, SCALE_E8M0);       \
            acc[m][3] = __builtin_amdgcn_mfma_scale_f32_16x16x128_f8f6f4(      \
                a8, b83, acc[m][3], 4, 4, 0, SCALE_E8M0, 0, SCALE_E8M0);       \
        }                                                                      \
        __builtin_amdgcn_s_setprio(0);                                         \
    } while (0)

    i32x4 A0[4], B0[4], A1[4], B1[4];
    LOADS(0, 0);
    STEP(0, 1, 0, false);
    STEP(1, 0, 1, false);
    STEP(0, 1, 2, false);
    STEP(1, 0, 3, false);
    STEP(0, 1, 4, false);
    STEP(1, 0, 5, false);
    STEP(0, 1, 6, false);
    STEP(1, 0, 7, true);
#undef LOADS
#undef BUILD8
#undef STEP

    // ---- epilogue: exp + masked row sums AND column sums ----
    int lab_r[16];
#pragma unroll
    for (int m = 0; m < 4; ++m)
#pragma unroll
        for (int r = 0; r < 4; ++r)
            lab_r[m * 4 + r] = labels[row0 + wr * 64 + m * 16 + lq * 4 + r];

    float rs_pos[16], rs_all[16];
#pragma unroll
    for (int i = 0; i < 16; ++i) { rs_pos[i] = 0.f; rs_all[i] = 0.f; }
    float cs_pos[4], cs_all[4];
#pragma unroll
    for (int n2 = 0; n2 < 4; ++n2) { cs_pos[n2] = 0.f; cs_all[n2] = 0.f; }

#pragma unroll
    for (int n2 = 0; n2 < 4; ++n2) {
        const int colg = col0 + wc * 64 + n2 * 16 + l15;
        const int lab_c = labels[colg];
#pragma unroll
        for (int m = 0; m < 4; ++m) {
#pragma unroll
            for (int r = 0; r < 4; ++r) {
                const int rowg = row0 + wr * 64 + m * 16 + lq * 4 + r;
                const float e = fast_exp2(acc[m][n2][r] * 14.4269504088896340736f);
                const bool self = (rowg == colg);       // only possible when diag
                const bool pos  = (lab_c == lab_r[m * 4 + r]) && !self;
                const float ea = self ? 0.f : e;
                const float ep = pos ? e : 0.f;
                rs_all[m * 4 + r] += ea;
                rs_pos[m * 4 + r] += ep;
                cs_all[n2] += ea;
                cs_pos[n2] += ep;
            }
        }
    }

#pragma unroll
    for (int i = 0; i < 16; ++i) {
#pragma unroll
        for (int d = 1; d < 16; d <<= 1) {
            rs_pos[i] += __shfl_xor(rs_pos[i], d, 64);
            rs_all[i] += __shfl_xor(rs_all[i], d, 64);
        }
    }
#pragma unroll
    for (int n2 = 0; n2 < 4; ++n2) {
#pragma unroll
        for (int d = 16; d < 64; d <<= 1) {
            cs_pos[n2] += __shfl_xor(cs_pos[n2], d, 64);
            cs_all[n2] += __shfl_xor(cs_all[n2], d, 64);
        }
    }

    float* rowpos = sc;                    // [2][128] indexed [wc][localrow]
    float* rowall = sc + 256;
    float* colpos = sc + 512;              // [2][128] indexed [wr][localcol]
    float* colall = sc + 768;
    if (l15 == 0) {
#pragma unroll
        for (int i = 0; i < 16; ++i) {
            const int m = i >> 2, r = i & 3;
            const int lr = wr * 64 + m * 16 + lq * 4 + r;
            rowpos[wc * 128 + lr] = rs_pos[i];
            rowall[wc * 128 + lr] = rs_all[i];
        }
    }
    if (lq == 0 && !diag) {
#pragma unroll
        for (int n2 = 0; n2 < 4; ++n2) {
            const int lc = wc * 64 + n2 * 16 + l15;
            colpos[wr * 128 + lc] = cs_pos[n2];
            colall[wr * 128 + lc] = cs_all[n2];
        }
    }
    __syncthreads();

    // deterministic int64 fixed-point row accumulation (commutative-exact)
    if (tid < 128) {
        const float rp = rowpos[tid] + rowpos[128 + tid];
        const float ra = rowall[tid] + rowall[128 + tid];
        atomicAdd(&rsum_pos[row0 + tid], (u64)(rp * FIX2 + 0.5f));
        atomicAdd(&rsum_all[row0 + tid], (u64)(ra * FIX2 + 0.5f));
    } else if (!diag) {
        const int t2 = tid - 128;
        const float cp = colpos[t2] + colpos[128 + t2];
        const float ca = colall[t2] + colall[128 + t2];
        atomicAdd(&rsum_pos[col0 + t2], (u64)(cp * FIX2 + 0.5f));
        atomicAdd(&rsum_all[col0 + t2], (u64)(ca * FIX2 + 0.5f));
    }
}

// ---- Kernel 3: lean finalize: LDS hist + 1 row/thread, coalesced u64 reads ----
__global__ __launch_bounds__(256)
void finalize_kernel(const int* __restrict__ labels, const u64* __restrict__ rsum_pos,
                     const u64* __restrict__ rsum_all, u64* __restrict__ acc,
                     float* __restrict__ out) {
    __shared__ int hist[NUM_CLS];
    __shared__ float sred[4];
    __shared__ int scnt[4];
    const int tid = threadIdx.x;
    if (tid < NUM_CLS) hist[tid] = 0;
    __syncthreads();
    for (int i = tid; i < N_ROWS; i += 256) atomicAdd(&hist[labels[i]], 1);
    __syncthreads();

    const int i = blockIdx.x * 256 + tid;
    const u64 rp = rsum_pos[i];
    const u64 ra = rsum_all[i];
    const int cnt = hist[labels[i]] - 1;
    float lsum = 0.f;
    int vcnt = 0;
    if (cnt > 0) {
        const float p = fmaxf((float)((double)rp / (double)FIX2), 1e-30f);
        const float a = (float)((double)ra / (double)FIX2);
        lsum = logf(a) - logf(p) + logf((float)cnt);
        vcnt = 1;
    }
    const int lane = tid & 63, wid = tid >> 6;
#pragma unroll
    for (int d = 1; d < 64; d <<= 1) {
        lsum += __shfl_xor(lsum, d, 64);
        vcnt += __shfl_xor(vcnt, d, 64);
    }
    if (lane == 0) { sred[wid] = lsum; scnt[wid] = vcnt; }
    __syncthreads();
    if (tid == 0) {
        const double bs = (double)(sred[0] + sred[1] + sred[2] + sred[3]);
        const u64 S = (u64)(bs * FIXSCALE + 0.5);
        const u64 C = (u64)(scnt[0] + scnt[1] + scnt[2] + scnt[3]);
        atomicAdd(&acc[1], S);
        atomicAdd(&acc[2], C);
        __threadfence();
        const u64 tk = atomicAdd(&acc[0], 1ULL);
        if (tk == (u64)(NFIN - 1)) {
            volatile u64* va = acc;
            const double St = (double)va[1];
            const double Ct = (double)va[2];
            out[0] = (float)(St / FIXSCALE / Ct);
        }
    }
}

extern "C" void kernel_launch(void* const* d_in, const int* in_sizes, int n_in,
                              void* d_out, int out_size, void* d_ws, size_t ws_size,
                              hipStream_t stream) {
    const float* emb   = (const float*)d_in[0];
    const int* labels  = (const int*)d_in[1];
    float* out         = (float*)d_out;
    char* ws           = (char*)d_ws;

    unsigned char* xqT = (unsigned char*)ws;                     // 4 MB fp4, K-major (32 planes)
    u64* rsum_pos = (u64*)(ws + (size_t)32 * KSTRIDE);           // 64 KB
    u64* rsum_all = rsum_pos + N_ROWS;                           // 64 KB
    u64* acc      = rsum_all + N_ROWS;                           // 32 B

    norm_kernel<<<N_ROWS / 16, 256, 0, stream>>>(emb, xqT, rsum_pos, rsum_all, acc);
    simloss_kernel<<<GRID_K2, 256, 0, stream>>>(xqT, labels, rsum_pos, rsum_all);
    finalize_kernel<<<NFIN, 256, 0, stream>>>(labels, rsum_pos, rsum_all, acc, out);
}